// Round 5
// baseline (314.573 us; speedup 1.0000x reference)
//
#include <hip/hip_runtime.h>

#define HID 20
#define NLAY 7

typedef float v2f __attribute__((ext_vector_type(2)));

__device__ __forceinline__ v2f vfma(v2f a, v2f b, v2f c) {
    return __builtin_elementwise_fma(a, b, c);
}

// tanh and its first three derivatives, via one hardware exp.
__device__ __forceinline__ float tanh_derivs(float a, float& d1, float& d2, float& d3) {
    const float e = __expf(2.0f * a);
    const float s = 1.0f - __fdividef(2.0f, e + 1.0f);
    d1 = 1.0f - s * s;               // f'
    d2 = -2.0f * s * d1;             // f''
    d3 = -2.0f * (d1 * d1 + s * d2); // f'''
    return s;
}

// Single 11-component jet per point:
// pairs: q0=(val,gt) q1=(gx,gy) q2=(hxx,hyy) q3=(hxt,hyt) q4=(Lx,Ly), scalar: hxy
// Lx = psi_xxx + psi_xyy, Ly = psi_xxy + psi_yyy.
__global__ void __launch_bounds__(256, 1)
pinn_kernel(const float* __restrict__ xs, const float* __restrict__ ys, const float* __restrict__ ts,
            const float* __restrict__ W_in, const float* __restrict__ b_in,
            const float* __restrict__ W_hid, const float* __restrict__ b_hid,
            const float* __restrict__ W_out, const float* __restrict__ b_out,
            const float* __restrict__ lam1p, const float* __restrict__ lam2p,
            float* __restrict__ out, int N)
{
    const int idx = blockIdx.x * blockDim.x + threadIdx.x;
    if (idx >= N) return;
    const float xv = xs[idx], yv = ys[idx], tv = ts[idx];
    const float l1 = lam1p[0], l2 = lam2p[0];

    v2f h[HID][5];
    float hxy[HID];

    // ---- input layer: a = w0*x + w1*y + w2*t + b ----
    #pragma unroll
    for (int j = 0; j < HID; ++j) {
        const float w0 = W_in[j], w1 = W_in[HID + j], w2 = W_in[2 * HID + j];
        const float a0 = fmaf(xv, w0, fmaf(yv, w1, fmaf(tv, w2, b_in[j])));
        float d1, d2, d3;
        const float s = tanh_derivs(a0, d1, d2, d3);
        const float g2w = w0 * w0 + w1 * w1;
        h[j][0] = (v2f){s, d1 * w2};
        h[j][1] = (v2f){d1 * w0, d1 * w1};
        h[j][2] = (v2f){d2 * w0 * w0, d2 * w1 * w1};
        h[j][3] = (v2f){d2 * w0 * w2, d2 * w1 * w2};
        h[j][4] = (v2f){d3 * w0 * g2w, d3 * w1 * g2w};
        hxy[j] = d2 * w0 * w1;
    }

    // ---- hidden layers (j-outer: 11 hot accumulators, h streamed read-only,
    //      hn write-once; all indices compile-time) ----
    #pragma unroll 1
    for (int l = 0; l < NLAY; ++l) {
        const float* __restrict__ Wl = W_hid + l * HID * HID;
        const float* __restrict__ bl = b_hid + l * HID;
        v2f hn[HID][5];
        float hnxy[HID];
        #pragma unroll
        for (int j = 0; j < HID; ++j) {
            v2f a0 = (v2f){bl[j], 0.0f};
            v2f a1 = (v2f){0.0f, 0.0f};
            v2f a2 = (v2f){0.0f, 0.0f};
            v2f a3 = (v2f){0.0f, 0.0f};
            v2f a4 = (v2f){0.0f, 0.0f};
            float axy = 0.0f;
            #pragma unroll
            for (int i = 0; i < HID; ++i) {
                const float w = Wl[i * HID + j];
                const v2f ww = (v2f){w, w};
                a0 = vfma(ww, h[i][0], a0);
                a1 = vfma(ww, h[i][1], a1);
                a2 = vfma(ww, h[i][2], a2);
                a3 = vfma(ww, h[i][3], a3);
                a4 = vfma(ww, h[i][4], a4);
                axy = fmaf(w, hxy[i], axy);
            }
            float d1, d2, d3;
            const float s   = tanh_derivs(a0.x, d1, d2, d3);
            const float agt = a0.y;
            const float agx = a1.x, agy = a1.y;
            const float ahxx = a2.x, ahyy = a2.y;
            const float ahxt = a3.x, ahyt = a3.y;
            const float aLx = a4.x, aLy = a4.y;
            const float ahxy = axy;
            const float g2 = agx * agx + agy * agy;
            hn[j][0] = (v2f){s, d1 * agt};
            hn[j][1] = (v2f){d1 * agx, d1 * agy};
            hn[j][2] = (v2f){fmaf(d2, agx * agx, d1 * ahxx),
                             fmaf(d2, agy * agy, d1 * ahyy)};
            hn[j][3] = (v2f){fmaf(d2, agx * agt, d1 * ahxt),
                             fmaf(d2, agy * agt, d1 * ahyt)};
            hn[j][4] = (v2f){d3 * agx * g2 + d2 * (3.0f * agx * ahxx + 2.0f * agy * ahxy + agx * ahyy) + d1 * aLx,
                             d3 * agy * g2 + d2 * (3.0f * agy * ahyy + 2.0f * agx * ahxy + agy * ahxx) + d1 * aLy};
            hnxy[j] = fmaf(d2, agx * agy, d1 * ahxy);
        }
        #pragma unroll
        for (int j = 0; j < HID; ++j) {
            h[j][0] = hn[j][0];
            h[j][1] = hn[j][1];
            h[j][2] = hn[j][2];
            h[j][3] = hn[j][3];
            h[j][4] = hn[j][4];
            hxy[j] = hnxy[j];
        }
    }

    // ---- output layer: psi = col 0, p = col 1 ----
    v2f ps0 = (v2f){0, 0}, ps1 = (v2f){0, 0}, ps2 = (v2f){0, 0}, ps3 = (v2f){0, 0}, ps4 = (v2f){0, 0};
    float psxy = 0.0f;
    float pv = 0.0f;
    v2f pg = (v2f){0, 0};
    #pragma unroll
    for (int i = 0; i < HID; ++i) {
        const float w0 = W_out[2 * i], w1 = W_out[2 * i + 1];
        const v2f w00 = (v2f){w0, w0};
        ps0 = vfma(w00, h[i][0], ps0);
        ps1 = vfma(w00, h[i][1], ps1);
        ps2 = vfma(w00, h[i][2], ps2);
        ps3 = vfma(w00, h[i][3], ps3);
        ps4 = vfma(w00, h[i][4], ps4);
        psxy = fmaf(w0, hxy[i], psxy);
        pv   = fmaf(w1, h[i][0].x, pv);
        pg   = vfma((v2f){w1, w1}, h[i][1], pg);
    }

    const float u = ps1.y;          // psi_y
    const float v = -ps1.x;         // -psi_x
    const float p = pv + b_out[1];
    const float ux = psxy;          // psi_yx
    const float uy = ps2.y;         // psi_yy
    const float vx = -ps2.x;        // -psi_xx
    const float vy = -psxy;         // -psi_xy
    const float px = pg.x, py = pg.y;
    const float lx = ps4.x, ly = ps4.y;
    const float ut = ps3.y;         // psi_yt
    const float vt = -ps3.x;        // -psi_xt

    const float fu = ut + l1 * (u * ux + v * uy) + px - l2 * ly;
    const float fv = vt + l1 * (u * vx + v * vy) + py + l2 * lx;

    out[idx]         = u;
    out[N + idx]     = v;
    out[2 * N + idx] = p;
    out[3 * N + idx] = fu;
    out[4 * N + idx] = fv;
}

extern "C" void kernel_launch(void* const* d_in, const int* in_sizes, int n_in,
                              void* d_out, int out_size, void* d_ws, size_t ws_size,
                              hipStream_t stream) {
    const float* xs    = (const float*)d_in[0];
    const float* ys    = (const float*)d_in[1];
    const float* ts    = (const float*)d_in[2];
    const float* W_in  = (const float*)d_in[3];
    const float* b_in  = (const float*)d_in[4];
    const float* W_hid = (const float*)d_in[5];
    const float* b_hid = (const float*)d_in[6];
    const float* W_out = (const float*)d_in[7];
    const float* b_out = (const float*)d_in[8];
    const float* lam1  = (const float*)d_in[9];
    const float* lam2  = (const float*)d_in[10];
    float* out = (float*)d_out;

    const int N = in_sizes[0];
    const int block = 256;
    const int grid = (N + block - 1) / block;
    pinn_kernel<<<grid, block, 0, stream>>>(xs, ys, ts, W_in, b_in, W_hid, b_hid,
                                            W_out, b_out, lam1, lam2, out, N);
}

// Round 6
// 176.430 us; speedup vs baseline: 1.7830x; 1.7830x over previous
//
#include <hip/hip_runtime.h>

#define HID 20
#define NLAY 7
#define NC 11
// comp indices: 0=val 1=gx 2=gy 3=gt 4=hxx 5=hxy 6=hyy 7=hxt 8=hyt 9=Lx 10=Ly

// Pin a value into an AGPR (write) / pull it back (read).
#define AGPR_WRITE(dst, src) asm("v_accvgpr_write_b32 %0, %1" : "=a"(dst) : "v"(src))
#define AGPR_READ(dst, src)  asm("v_accvgpr_read_b32 %0, %1" : "=v"(dst) : "a"(src))

// tanh and its first three derivatives, via one hardware exp.
__device__ __forceinline__ float tanh_derivs(float a, float& d1, float& d2, float& d3) {
    const float e = __expf(2.0f * a);
    const float s = 1.0f - __fdividef(2.0f, e + 1.0f);
    d1 = 1.0f - s * s;               // f'
    d2 = -2.0f * s * d1;             // f''
    d3 = -2.0f * (d1 * d1 + s * d2); // f'''
    return s;
}

__global__ void __launch_bounds__(256, 1)
pinn_kernel(const float* __restrict__ xs, const float* __restrict__ ys, const float* __restrict__ ts,
            const float* __restrict__ W_in, const float* __restrict__ b_in,
            const float* __restrict__ W_hid, const float* __restrict__ b_hid,
            const float* __restrict__ W_out, const float* __restrict__ b_out,
            const float* __restrict__ lam1p, const float* __restrict__ lam2p,
            float* __restrict__ out, int N)
{
    const int idx = blockIdx.x * blockDim.x + threadIdx.x;
    if (idx >= N) return;
    const float xv = xs[idx], yv = ys[idx], tv = ts[idx];
    const float l1 = lam1p[0], l2 = lam2p[0];

    float hA[HID][NC];  // jet state, pinned in AGPRs via asm below

    // ---- input layer ----
    #pragma unroll
    for (int j = 0; j < HID; ++j) {
        const float w0 = W_in[j], w1 = W_in[HID + j], w2 = W_in[2 * HID + j];
        const float a0 = fmaf(xv, w0, fmaf(yv, w1, fmaf(tv, w2, b_in[j])));
        float d1, d2, d3;
        const float s = tanh_derivs(a0, d1, d2, d3);
        const float g2w = w0 * w0 + w1 * w1;
        float nv[NC];
        nv[0] = s;
        nv[1] = d1 * w0;
        nv[2] = d1 * w1;
        nv[3] = d1 * w2;
        nv[4] = d2 * w0 * w0;
        nv[5] = d2 * w0 * w1;
        nv[6] = d2 * w1 * w1;
        nv[7] = d2 * w0 * w2;
        nv[8] = d2 * w1 * w2;
        nv[9] = d3 * w0 * g2w;
        nv[10] = d3 * w1 * g2w;
        #pragma unroll
        for (int c = 0; c < NC; ++c) AGPR_WRITE(hA[j][c], nv[c]);
    }

    // ---- hidden layers: i-outer, acc in VGPR (RMW), h streamed from AGPR ----
    #pragma unroll 1
    for (int l = 0; l < NLAY; ++l) {
        const float* __restrict__ Wl = W_hid + l * HID * HID;
        const float* __restrict__ bl = b_hid + l * HID;
        float acc[HID][NC];
        #pragma unroll
        for (int j = 0; j < HID; ++j) {
            acc[j][0] = bl[j];
            #pragma unroll
            for (int c = 1; c < NC; ++c) acc[j][c] = 0.0f;
        }
        #pragma unroll
        for (int i = 0; i < HID; ++i) {
            float r[NC];
            #pragma unroll
            for (int c = 0; c < NC; ++c) AGPR_READ(r[c], hA[i][c]);
            #pragma unroll
            for (int j = 0; j < HID; ++j) {
                const float w = Wl[i * HID + j];
                #pragma unroll
                for (int c = 0; c < NC; ++c) acc[j][c] = fmaf(w, r[c], acc[j][c]);
            }
        }
        #pragma unroll
        for (int j = 0; j < HID; ++j) {
            float d1, d2, d3;
            const float s = tanh_derivs(acc[j][0], d1, d2, d3);
            const float agx = acc[j][1], agy = acc[j][2], agt = acc[j][3];
            const float ahxx = acc[j][4], ahxy = acc[j][5], ahyy = acc[j][6];
            const float ahxt = acc[j][7], ahyt = acc[j][8];
            const float aLx = acc[j][9], aLy = acc[j][10];
            const float g2 = agx * agx + agy * agy;
            float nv[NC];
            nv[0] = s;
            nv[1] = d1 * agx;
            nv[2] = d1 * agy;
            nv[3] = d1 * agt;
            nv[4] = fmaf(d2, agx * agx, d1 * ahxx);
            nv[5] = fmaf(d2, agx * agy, d1 * ahxy);
            nv[6] = fmaf(d2, agy * agy, d1 * ahyy);
            nv[7] = fmaf(d2, agx * agt, d1 * ahxt);
            nv[8] = fmaf(d2, agy * agt, d1 * ahyt);
            nv[9]  = d3 * agx * g2 + d2 * (3.0f * agx * ahxx + 2.0f * agy * ahxy + agx * ahyy) + d1 * aLx;
            nv[10] = d3 * agy * g2 + d2 * (3.0f * agy * ahyy + 2.0f * agx * ahxy + agy * ahxx) + d1 * aLy;
            #pragma unroll
            for (int c = 0; c < NC; ++c) AGPR_WRITE(hA[j][c], nv[c]);
        }
    }

    // ---- output layer: psi = col 0, p = col 1 ----
    float su = 0, sv = 0, sp = 0, sux = 0, suy = 0, svx = 0;
    float spx = 0, spy = 0, sut = 0, svt = 0, slx = 0, sly = 0;
    #pragma unroll
    for (int i = 0; i < HID; ++i) {
        const float w0 = W_out[2 * i], w1 = W_out[2 * i + 1];
        float r[NC];
        #pragma unroll
        for (int c = 0; c < NC; ++c) AGPR_READ(r[c], hA[i][c]);
        sp  = fmaf(w1, r[0], sp);
        sv  = fmaf(w0, r[1], sv);   // psi_x
        su  = fmaf(w0, r[2], su);   // psi_y
        spx = fmaf(w1, r[1], spx);
        spy = fmaf(w1, r[2], spy);
        svx = fmaf(w0, r[4], svx);  // psi_xx
        sux = fmaf(w0, r[5], sux);  // psi_xy
        suy = fmaf(w0, r[6], suy);  // psi_yy
        svt = fmaf(w0, r[7], svt);  // psi_xt
        sut = fmaf(w0, r[8], sut);  // psi_yt
        slx = fmaf(w0, r[9], slx);
        sly = fmaf(w0, r[10], sly);
    }

    const float u = su;
    const float v = -sv;
    const float p = sp + b_out[1];
    const float ux = sux, uy = suy;
    const float vx = -svx, vy = -sux;
    const float px = spx, py = spy;
    const float ut = sut, vt = -svt;
    const float lx = slx, ly = sly;

    const float fu = ut + l1 * (u * ux + v * uy) + px - l2 * ly;
    const float fv = vt + l1 * (u * vx + v * vy) + py + l2 * lx;

    out[idx]         = u;
    out[N + idx]     = v;
    out[2 * N + idx] = p;
    out[3 * N + idx] = fu;
    out[4 * N + idx] = fv;
}

extern "C" void kernel_launch(void* const* d_in, const int* in_sizes, int n_in,
                              void* d_out, int out_size, void* d_ws, size_t ws_size,
                              hipStream_t stream) {
    const float* xs    = (const float*)d_in[0];
    const float* ys    = (const float*)d_in[1];
    const float* ts    = (const float*)d_in[2];
    const float* W_in  = (const float*)d_in[3];
    const float* b_in  = (const float*)d_in[4];
    const float* W_hid = (const float*)d_in[5];
    const float* b_hid = (const float*)d_in[6];
    const float* W_out = (const float*)d_in[7];
    const float* b_out = (const float*)d_in[8];
    const float* lam1  = (const float*)d_in[9];
    const float* lam2  = (const float*)d_in[10];
    float* out = (float*)d_out;

    const int N = in_sizes[0];
    const int block = 256;
    const int grid = (N + block - 1) / block;
    pinn_kernel<<<grid, block, 0, stream>>>(xs, ys, ts, W_in, b_in, W_hid, b_hid,
                                            W_out, b_out, lam1, lam2, out, N);
}